// Round 13
// baseline (36.029 us; speedup 1.0000x reference)
//
#include <hip/hip_runtime.h>

// Problem constants (B,S,H,D fixed by the reference)
#define BB   2
#define SS   2048
#define HH   16
#define DD   64
#define CC   128               // chunk length
#define NCH  (SS/CC)           // 16 chunks per (b,h)
#define RECF (DD*DD + DD)      // 4160 elems per record: State^T rows 0..63 + ksum row 64
#define BHN  (BB*HH)           // 32
#define NCHK (BHN*NCH)         // 512 chunk-blocks

typedef __attribute__((ext_vector_type(8))) short short8;
typedef __attribute__((ext_vector_type(4))) float f32x4;

// XOR swizzle of the s-index (units of 8 shorts) by LDS row (stride-136 tiles).
#define SW(r) ((((r) >> 3) & 7) << 3)
// XOR swizzle for the pad-free Kbh[64][64] tile: col (shorts) ^= (row&7)<<3.
#define SK(r) (((r) & 7) << 3)

__device__ __forceinline__ float elu1(float x) {
    return x > 0.0f ? x + 1.0f : __expf(x);
}
__device__ __forceinline__ short f2bf(float f) {
    union { float f; unsigned u; } x; x.f = f;
    unsigned r = x.u + 0x7FFFu + ((x.u >> 16) & 1u);   // RNE
    return (short)(r >> 16);
}
__device__ __forceinline__ float bf2f(short s) {
    union { unsigned u; float f; } x; x.u = ((unsigned)(unsigned short)s) << 16;
    return x.f;
}

// ---------------------------------------------------------------------------
// Kernel 1 (verbatim R9/R12): per-chunk State^T (+ksum row) = [V^T; ones] . K.
// ---------------------------------------------------------------------------
__global__ __launch_bounds__(512) void k_state(const float* __restrict__ qk,
                                               const float* __restrict__ v,
                                               short* __restrict__ rec_g) {
    const int blk = blockIdx.x;
    const int c   = blk % NCH;
    const int bh  = blk / NCH;
    const int b = bh / HH, h = bh % HH;
    const int tid = threadIdx.x;
    const int w   = tid >> 6;
    const int l   = tid & 63;
    const int l15 = l & 15;
    const int g   = l >> 4;

    __shared__ short KT[64][136];   // K^T, swizzled cols
    __shared__ short VT[65][136];   // V^T + ones row 64

#pragma unroll
    for (int it = 0; it < 4; ++it) {
        const int f    = tid + it*512;      // float4 index 0..2047
        const int row  = f >> 4;            // s in chunk, 0..127
        const int col4 = (f & 15) * 4;      // d
        const int s = c*CC + row;
        float4 kq = *(const float4*)(qk + ((((size_t)b*SS + s)*2 + 1)*HH + h)*DD + col4);
        KT[col4+0][row ^ SW(col4+0)] = f2bf(elu1(kq.x));
        KT[col4+1][row ^ SW(col4+1)] = f2bf(elu1(kq.y));
        KT[col4+2][row ^ SW(col4+2)] = f2bf(elu1(kq.z));
        KT[col4+3][row ^ SW(col4+3)] = f2bf(elu1(kq.w));
        float4 vv = *(const float4*)(v + (((size_t)b*SS + s)*HH + h)*DD + col4);
        VT[col4+0][row ^ SW(col4+0)] = f2bf(vv.x);
        VT[col4+1][row ^ SW(col4+1)] = f2bf(vv.y);
        VT[col4+2][row ^ SW(col4+2)] = f2bf(vv.z);
        VT[col4+3][row ^ SW(col4+3)] = f2bf(vv.w);
    }
    if (tid < 128) VT[64][tid] = (short)0x3F80;   // ones row (SW(64)==0)
    __syncthreads();

    const int dtile = w & 3;
    const int half  = w >> 2;
    const int nrt   = half ? 2 : 3;
    const int rt0   = half ? 3 : 0;
    f32x4 acc1[3];
#pragma unroll
    for (int i = 0; i < 3; ++i) acc1[i] = (f32x4){0.f,0.f,0.f,0.f};
    const int krow = 16*dtile + l15;
#pragma unroll
    for (int ks = 0; ks < 4; ++ks) {
        const int cb = 32*ks + 8*g;
        short8 bk = *(const short8*)(&KT[krow][cb ^ SW(krow)]);
#pragma unroll
        for (int i = 0; i < 3; ++i) {
            if (i < nrt) {
                int arow = 16*(rt0 + i) + l15;
                if (arow > 64) arow = 64;          // clamp into ones row
                short8 a = *(const short8*)(&VT[arow][cb ^ SW(arow)]);
                acc1[i] = __builtin_amdgcn_mfma_f32_16x16x32_bf16(a, bk, acc1[i], 0, 0, 0);
            }
        }
    }
    short* rec = rec_g + (size_t)blk * RECF;
#pragma unroll
    for (int i = 0; i < 3; ++i) {
        if (i < nrt) {
            const int rt = rt0 + i;
            if (rt < 4) {
#pragma unroll
                for (int e = 0; e < 4; ++e)
                    rec[(16*rt + 4*g + e)*DD + 16*dtile + l15] = f2bf(acc1[i][e]);
            } else if (g == 0) {
                rec[4096 + 16*dtile + l15] = f2bf(acc1[i][0]);   // ksum row
            }
        }
    }
}

// ---------------------------------------------------------------------------
// Kernel 2: O = [S | Q] . [V;ones ; State_prefix^T;ksum], S = mask(Q K^T).
// Two-pass S with half-K tile staged twice (second half loaded in phase 0,
// LDS-written under the SV-A MFMAs). LDS 53,664 B -> 3 blocks/CU; VGPR
// capped for 6 waves/SIMD. Accumulation order identical to R9/R12.
// ---------------------------------------------------------------------------
__global__ __launch_bounds__(512, 6) void k_out(const float* __restrict__ qk,
                                                const float* __restrict__ v,
                                                const short* __restrict__ rec_g,
                                                float* __restrict__ out) {
    const int blk = blockIdx.x;
    const int c   = blk % NCH;
    const int bh  = blk / NCH;
    const int b = bh / HH, h = bh % HH;
    const int tid = threadIdx.x;
    const int w   = tid >> 6;
    const int l   = tid & 63;
    const int l15 = l & 15;
    const int g   = l >> 4;

    __shared__ short Kbh[64][64];   // half K tile, XOR-swizzled   8192 B
    __shared__ short Sbh[128][72];  // score half (two passes)    18432 B
    __shared__ short StT[65][72];   // prefix State^T + ksum row   9360 B
    __shared__ short VT[65][136];   // V^T + ones row 64          17680 B

    // ---- VT staging (transposed scalar writes, R12 pattern) ----
#pragma unroll
    for (int it = 0; it < 4; ++it) {
        const int f    = tid + it*512;      // float4 index 0..2047
        const int row  = f >> 4;
        const int col4 = (f & 15) * 4;
        const int s = c*CC + row;
        float4 vv = *(const float4*)(v + (((size_t)b*SS + s)*HH + h)*DD + col4);
        VT[col4+0][row ^ SW(col4+0)] = f2bf(vv.x);
        VT[col4+1][row ^ SW(col4+1)] = f2bf(vv.y);
        VT[col4+2][row ^ SW(col4+2)] = f2bf(vv.z);
        VT[col4+3][row ^ SW(col4+3)] = f2bf(vv.w);
    }
    if (tid < 128) VT[64][tid] = (short)0x3F80;   // ones row

    // ---- Kbh pass-A staging (K rows 0..63) ----
#pragma unroll
    for (int it = 0; it < 2; ++it) {
        const int f    = tid + it*512;      // 0..1023
        const int row  = f >> 4;            // 0..63
        const int col4 = (f & 15) * 4;
        const int s = c*CC + row;
        float4 kq = *(const float4*)(qk + ((((size_t)b*SS + s)*2 + 1)*HH + h)*DD + col4);
        short4 kb;
        kb.x = f2bf(elu1(kq.x)); kb.y = f2bf(elu1(kq.y));
        kb.z = f2bf(elu1(kq.z)); kb.w = f2bf(elu1(kq.w));
        *(short4*)(&Kbh[row][col4 ^ SK(row)]) = kb;
    }

    // ---- Kbh pass-B data (K rows 64..127): load+convert now, LDS-write later
    short4 kbB[2];
#pragma unroll
    for (int it = 0; it < 2; ++it) {
        const int f    = tid + it*512;
        const int row  = 64 + (f >> 4);     // 64..127
        const int col4 = (f & 15) * 4;
        const int s = c*CC + row;
        float4 kq = *(const float4*)(qk + ((((size_t)b*SS + s)*2 + 1)*HH + h)*DD + col4);
        kbB[it].x = f2bf(elu1(kq.x)); kbB[it].y = f2bf(elu1(kq.y));
        kbB[it].z = f2bf(elu1(kq.z)); kbB[it].w = f2bf(elu1(kq.w));
    }

    // ---- Q fragments (elu1 -> bf16) ----
    const int qrow = 16*w + l15;
    const float* qp = qk + ((((size_t)b*SS + (c*CC + qrow))*2 + 0)*HH + h)*DD;
    short8 aq[2];
#pragma unroll
    for (int ks = 0; ks < 2; ++ks) {
        const int k0 = 32*ks + 8*g;
        float4 t0 = *(const float4*)(qp + k0);
        float4 t1 = *(const float4*)(qp + k0 + 4);
        short8 a;
        a[0] = f2bf(elu1(t0.x)); a[1] = f2bf(elu1(t0.y));
        a[2] = f2bf(elu1(t0.z)); a[3] = f2bf(elu1(t0.w));
        a[4] = f2bf(elu1(t1.x)); a[5] = f2bf(elu1(t1.y));
        a[6] = f2bf(elu1(t1.z)); a[7] = f2bf(elu1(t1.w));
        aq[ks] = a;
    }

    // ---- lookback: 3 pipelined groups of 5 (ascending p; VGPR-bounded) ----
    {
        const short* base = rec_g + (size_t)(bh*NCH) * RECF;
        float pf[8] = {0.f,0.f,0.f,0.f,0.f,0.f,0.f,0.f};
        short8 rva[5], rvb[5];
#pragma unroll
        for (int i = 0; i < 5; ++i)
            if (i < c) rva[i] = *(const short8*)(base + (size_t)i*RECF + tid*8);
#pragma unroll
        for (int i = 0; i < 5; ++i)
            if (5+i < c) rvb[i] = *(const short8*)(base + (size_t)(5+i)*RECF + tid*8);
#pragma unroll
        for (int i = 0; i < 5; ++i)
            if (i < c)
#pragma unroll
                for (int e = 0; e < 8; ++e) pf[e] += bf2f(rva[i][e]);
#pragma unroll
        for (int i = 0; i < 5; ++i)
            if (10+i < c) rva[i] = *(const short8*)(base + (size_t)(10+i)*RECF + tid*8);
#pragma unroll
        for (int i = 0; i < 5; ++i)
            if (5+i < c)
#pragma unroll
                for (int e = 0; e < 8; ++e) pf[e] += bf2f(rvb[i][e]);
#pragma unroll
        for (int i = 0; i < 5; ++i)
            if (10+i < c)
#pragma unroll
                for (int e = 0; e < 8; ++e) pf[e] += bf2f(rva[i][e]);

        short8 sv;
#pragma unroll
        for (int e = 0; e < 8; ++e) sv[e] = f2bf(pf[e]);
        *(short8*)(&StT[tid >> 3][(tid & 7) * 8]) = sv;

        if (tid < 64) {                             // ksum row: one elem/lane
            float ps = 0.f;
#pragma unroll
            for (int p = 0; p < 15; ++p)
                if (p < c) ps += bf2f(base[(size_t)p*RECF + 4096 + tid]);
            StT[64][tid] = f2bf(ps);
        }
    }
    __syncthreads();   // sync1: VT, Kbh-A, StT ready

    const int rowb = 16*w + 4*g;

    // ---- S pass A: global cols 0..63 from Kbh (rows 0..63) ----
#pragma unroll
    for (int tc = 0; tc < 4; ++tc) {
        const int kr = 16*tc + l15;
        f32x4 sacc = {0.f,0.f,0.f,0.f};
#pragma unroll
        for (int ks = 0; ks < 2; ++ks) {
            short8 bk = *(const short8*)(&Kbh[kr][(32*ks + 8*g) ^ SK(kr)]);
            sacc = __builtin_amdgcn_mfma_f32_16x16x32_bf16(aq[ks], bk, sacc, 0, 0, 0);
        }
        const int colg = 16*tc + l15;
#pragma unroll
        for (int e = 0; e < 4; ++e) {
            const float sv = (colg <= rowb + e) ? sacc[e] : 0.0f;
            Sbh[rowb + e][colg] = f2bf(sv);
        }
    }
    __syncthreads();   // sync2: Sbh-A ready, Kbh-A reads done

    // ---- Kbh pass-B LDS writes (hidden under the MFMAs below) ----
#pragma unroll
    for (int it = 0; it < 2; ++it) {
        const int f    = tid + it*512;
        const int row  = f >> 4;            // local row 0..63 (global 64..127)
        const int col4 = (f & 15) * 4;
        *(short4*)(&Kbh[row][col4 ^ SK(row)]) = kbB[it];
    }

    // ---- O = S_A.V (kj 0,1) + Q.State^T (kd 0,1); tile 4 = denominator ----
    f32x4 acc[5];
#pragma unroll
    for (int t = 0; t < 5; ++t) acc[t] = (f32x4){0.f,0.f,0.f,0.f};
#pragma unroll
    for (int kj = 0; kj < 2; ++kj) {
        short8 as = *(const short8*)(&Sbh[16*w + l15][32*kj + 8*g]);
#pragma unroll
        for (int tc = 0; tc < 5; ++tc) {
            int vrow = 16*tc + l15;
            if (vrow > 64) vrow = 64;              // clamp into ones row
            short8 bv = *(const short8*)(&VT[vrow][(32*kj + 8*g) ^ SW(vrow)]);
            acc[tc] = __builtin_amdgcn_mfma_f32_16x16x32_bf16(as, bv, acc[tc], 0, 0, 0);
        }
    }
#pragma unroll
    for (int kd = 0; kd < 2; ++kd) {
#pragma unroll
        for (int tc = 0; tc < 5; ++tc) {
            int srow = 16*tc + l15;
            if (srow > 64) srow = 64;              // clamp into ksum row
            short8 bs = *(const short8*)(&StT[srow][32*kd + 8*g]);
            acc[tc] = __builtin_amdgcn_mfma_f32_16x16x32_bf16(aq[kd], bs, acc[tc], 0, 0, 0);
        }
    }
    __syncthreads();   // sync3: Kbh-B visible; Sbh-A reads done

    // ---- S pass B: global cols 64..127 from Kbh (rows 64..127) ----
#pragma unroll
    for (int tc = 4; tc < 8; ++tc) {
        const int kr = 16*(tc-4) + l15;
        f32x4 sacc = {0.f,0.f,0.f,0.f};
#pragma unroll
        for (int ks = 0; ks < 2; ++ks) {
            short8 bk = *(const short8*)(&Kbh[kr][(32*ks + 8*g) ^ SK(kr)]);
            sacc = __builtin_amdgcn_mfma_f32_16x16x32_bf16(aq[ks], bk, sacc, 0, 0, 0);
        }
        const int colg = 16*tc + l15;
#pragma unroll
        for (int e = 0; e < 4; ++e) {
            const float sv = (colg <= rowb + e) ? sacc[e] : 0.0f;
            Sbh[rowb + e][colg - 64] = f2bf(sv);
        }
    }
    __syncthreads();   // sync4: Sbh-B ready

    // ---- O += S_B.V (kj 2,3; global s = 64 + local) ----
#pragma unroll
    for (int kj = 2; kj < 4; ++kj) {
        short8 as = *(const short8*)(&Sbh[16*w + l15][32*(kj-2) + 8*g]);
#pragma unroll
        for (int tc = 0; tc < 5; ++tc) {
            int vrow = 16*tc + l15;
            if (vrow > 64) vrow = 64;
            short8 bv = *(const short8*)(&VT[vrow][(32*kj + 8*g) ^ SW(vrow)]);
            acc[tc] = __builtin_amdgcn_mfma_f32_16x16x32_bf16(as, bv, acc[tc], 0, 0, 0);
        }
    }

    // ---- epilogue: acc[4][e] IS the denominator in every lane ----
    float rn[4];
#pragma unroll
    for (int e = 0; e < 4; ++e) rn[e] = 1.0f / acc[4][e];
    const int rowg = c*CC + rowb;
#pragma unroll
    for (int e = 0; e < 4; ++e) {
        float* orow = out + (((size_t)b*SS + rowg + e)*HH + h)*DD + l15;
#pragma unroll
        for (int tc = 0; tc < 4; ++tc) orow[16*tc] = acc[tc][e] * rn[e];
    }
}

// ---------------------------------------------------------------------------
extern "C" void kernel_launch(void* const* d_in, const int* in_sizes, int n_in,
                              void* d_out, int out_size, void* d_ws, size_t ws_size,
                              hipStream_t stream) {
    const float* qk = (const float*)d_in[0];
    const float* v  = (const float*)d_in[1];
    float* out = (float*)d_out;

    short* rec_g = (short*)d_ws;        // 512*4160 bf16 = 4.26 MB

    k_state<<<dim3(NCHK), dim3(512), 0, stream>>>(qk, v, rec_g);
    k_out  <<<dim3(NCHK), dim3(512), 0, stream>>>(qk, v, rec_g, out);
}

// Round 14
// 30.413 us; speedup vs baseline: 1.1847x; 1.1847x over previous
//
#include <hip/hip_runtime.h>

// Problem constants (B,S,H,D fixed by the reference)
#define BB   2
#define SS   2048
#define HH   16
#define DD   64
#define CC   128               // chunk length
#define NCH  (SS/CC)           // 16 chunks per (b,h)
#define RECF (DD*DD + DD)      // 4160 elems per record: State^T rows 0..63 + ksum row 64
#define BHN  (BB*HH)           // 32
#define NCHK (BHN*NCH)         // 512 chunk-blocks

typedef __attribute__((ext_vector_type(8))) short short8;
typedef __attribute__((ext_vector_type(4))) float f32x4;

// XOR swizzle of the s-index (units of 8 shorts) by LDS row.
#define SW(r) ((((r) >> 3) & 7) << 3)

__device__ __forceinline__ float elu1(float x) {
    return x > 0.0f ? x + 1.0f : __expf(x);
}
__device__ __forceinline__ short f2bf(float f) {
    union { float f; unsigned u; } x; x.f = f;
    unsigned r = x.u + 0x7FFFu + ((x.u >> 16) & 1u);   // RNE
    return (short)(r >> 16);
}
__device__ __forceinline__ float bf2f(short s) {
    union { unsigned u; float f; } x; x.u = ((unsigned)(unsigned short)s) << 16;
    return x.f;
}
// pack two bf16 into one dword: lo -> short[0], hi -> short[1]
__device__ __forceinline__ unsigned pack2(float lo, float hi) {
    return (unsigned)(unsigned short)f2bf(lo)
         | ((unsigned)(unsigned short)f2bf(hi) << 16);
}

// ---------------------------------------------------------------------------
// Kernel 1 (R9 structure): per-chunk State^T (+ksum row) = [V^T; ones] . K.
// Sole change vs R9: transposed KT/VT writes are packed row-pair dwords
// (one lane per dword, 2 lanes/bank across the wave -> conflict-free).
// ---------------------------------------------------------------------------
__global__ __launch_bounds__(512) void k_state(const float* __restrict__ qk,
                                               const float* __restrict__ v,
                                               short* __restrict__ rec_g) {
    const int blk = blockIdx.x;
    const int c   = blk % NCH;
    const int bh  = blk / NCH;
    const int b = bh / HH, h = bh % HH;
    const int tid = threadIdx.x;
    const int w   = tid >> 6;
    const int l   = tid & 63;
    const int l15 = l & 15;
    const int g   = l >> 4;

    __shared__ short KT[64][136];   // K^T, swizzled cols
    __shared__ short VT[65][136];   // V^T + ones row 64

    // packed-pair staging: pi = row-pair r (0..63) x col4-group (0..15)
#pragma unroll
    for (int it = 0; it < 2; ++it) {
        const int pi   = tid + it*512;      // 0..1023
        const int r    = pi >> 4;           // row-pair index
        const int col4 = (pi & 15) * 4;     // d base
        const int s0 = c*CC + 2*r;
        const float* kp = qk + ((((size_t)b*SS + s0)*2 + 1)*HH + h)*DD + col4;
        float4 k0 = *(const float4*)kp;
        float4 k1 = *(const float4*)(kp + 2*HH*DD);   // row s0+1 (qk stride 2*H*D)
        const float* vp = v + (((size_t)b*SS + s0)*HH + h)*DD + col4;
        float4 v0 = *(const float4*)vp;
        float4 v1 = *(const float4*)(vp + HH*DD);     // row s0+1
        const int s2 = 2*r;
        *(unsigned*)(&KT[col4+0][s2 ^ SW(col4+0)]) = pack2(elu1(k0.x), elu1(k1.x));
        *(unsigned*)(&KT[col4+1][s2 ^ SW(col4+1)]) = pack2(elu1(k0.y), elu1(k1.y));
        *(unsigned*)(&KT[col4+2][s2 ^ SW(col4+2)]) = pack2(elu1(k0.z), elu1(k1.z));
        *(unsigned*)(&KT[col4+3][s2 ^ SW(col4+3)]) = pack2(elu1(k0.w), elu1(k1.w));
        *(unsigned*)(&VT[col4+0][s2 ^ SW(col4+0)]) = pack2(v0.x, v1.x);
        *(unsigned*)(&VT[col4+1][s2 ^ SW(col4+1)]) = pack2(v0.y, v1.y);
        *(unsigned*)(&VT[col4+2][s2 ^ SW(col4+2)]) = pack2(v0.z, v1.z);
        *(unsigned*)(&VT[col4+3][s2 ^ SW(col4+3)]) = pack2(v0.w, v1.w);
    }
    if (tid < 64) *(unsigned*)(&VT[64][2*tid]) = 0x3F803F80u;   // ones row (SW(64)==0)
    __syncthreads();

    const int dtile = w & 3;
    const int half  = w >> 2;
    const int nrt   = half ? 2 : 3;
    const int rt0   = half ? 3 : 0;
    f32x4 acc1[3];
#pragma unroll
    for (int i = 0; i < 3; ++i) acc1[i] = (f32x4){0.f,0.f,0.f,0.f};
    const int krow = 16*dtile + l15;
#pragma unroll
    for (int ks = 0; ks < 4; ++ks) {
        const int cb = 32*ks + 8*g;
        short8 bk = *(const short8*)(&KT[krow][cb ^ SW(krow)]);
#pragma unroll
        for (int i = 0; i < 3; ++i) {
            if (i < nrt) {
                int arow = 16*(rt0 + i) + l15;
                if (arow > 64) arow = 64;          // clamp into ones row
                short8 a = *(const short8*)(&VT[arow][cb ^ SW(arow)]);
                acc1[i] = __builtin_amdgcn_mfma_f32_16x16x32_bf16(a, bk, acc1[i], 0, 0, 0);
            }
        }
    }
    short* rec = rec_g + (size_t)blk * RECF;
#pragma unroll
    for (int i = 0; i < 3; ++i) {
        if (i < nrt) {
            const int rt = rt0 + i;
            if (rt < 4) {
#pragma unroll
                for (int e = 0; e < 4; ++e)
                    rec[(16*rt + 4*g + e)*DD + 16*dtile + l15] = f2bf(acc1[i][e]);
            } else if (g == 0) {
                rec[4096 + 16*dtile + l15] = f2bf(acc1[i][0]);   // ksum row
            }
        }
    }
}

// ---------------------------------------------------------------------------
// Kernel 2 (R9 structure, verbatim phases): O = [S | Q].[V;ones ; StT;ksum].
// Sole change vs R9: VT transposed writes are packed row-pair dwords.
// LDS 63.9 KB -> 2 blocks/CU.
// ---------------------------------------------------------------------------
__global__ __launch_bounds__(512) void k_out(const float* __restrict__ qk,
                                             const float* __restrict__ v,
                                             const short* __restrict__ rec_g,
                                             float* __restrict__ out) {
    const int blk = blockIdx.x;
    const int c   = blk % NCH;
    const int bh  = blk / NCH;
    const int b = bh / HH, h = bh % HH;
    const int tid = threadIdx.x;
    const int w   = tid >> 6;
    const int l   = tid & 63;
    const int l15 = l & 15;
    const int g   = l >> 4;

    __shared__ short Sbh[128][72];  // score half (two passes)        18432 B
    __shared__ short StT[65][72];   // prefix State^T + ksum row 64    9360 B
    __shared__ short VT[65][136];   // V^T + ones row 64              17680 B
    __shared__ short Kb[128][72];   // K row-major bf16               18432 B

    // ---- K staging (R9 mapping: coalesced float4 -> short4 row-major) ----
#pragma unroll
    for (int it = 0; it < 4; ++it) {
        const int f    = tid + it*512;      // float4 index 0..2047
        const int row  = f >> 4;
        const int col4 = (f & 15) * 4;
        const int s = c*CC + row;
        float4 kq = *(const float4*)(qk + ((((size_t)b*SS + s)*2 + 1)*HH + h)*DD + col4);
        short4 kb;
        kb.x = f2bf(elu1(kq.x)); kb.y = f2bf(elu1(kq.y));
        kb.z = f2bf(elu1(kq.z)); kb.w = f2bf(elu1(kq.w));
        *(short4*)(&Kb[row][col4]) = kb;
    }
    // ---- V staging: packed row-pair dword transpose ----
#pragma unroll
    for (int it = 0; it < 2; ++it) {
        const int pi   = tid + it*512;      // 0..1023
        const int r    = pi >> 4;
        const int col4 = (pi & 15) * 4;
        const int s0 = c*CC + 2*r;
        const float* vp = v + (((size_t)b*SS + s0)*HH + h)*DD + col4;
        float4 v0 = *(const float4*)vp;
        float4 v1 = *(const float4*)(vp + HH*DD);
        const int s2 = 2*r;
        *(unsigned*)(&VT[col4+0][s2 ^ SW(col4+0)]) = pack2(v0.x, v1.x);
        *(unsigned*)(&VT[col4+1][s2 ^ SW(col4+1)]) = pack2(v0.y, v1.y);
        *(unsigned*)(&VT[col4+2][s2 ^ SW(col4+2)]) = pack2(v0.z, v1.z);
        *(unsigned*)(&VT[col4+3][s2 ^ SW(col4+3)]) = pack2(v0.w, v1.w);
    }
    if (tid < 64) *(unsigned*)(&VT[64][2*tid]) = 0x3F803F80u;   // ones row

    // ---- Q fragments (elu1 -> bf16), R9 ----
    const int qrow = 16*w + l15;
    const float* qp = qk + ((((size_t)b*SS + (c*CC + qrow))*2 + 0)*HH + h)*DD;
    short8 aq[2];
#pragma unroll
    for (int ks = 0; ks < 2; ++ks) {
        const int k0 = 32*ks + 8*g;
        float4 t0 = *(const float4*)(qp + k0);
        float4 t1 = *(const float4*)(qp + k0 + 4);
        short8 a;
        a[0] = f2bf(elu1(t0.x)); a[1] = f2bf(elu1(t0.y));
        a[2] = f2bf(elu1(t0.z)); a[3] = f2bf(elu1(t0.w));
        a[4] = f2bf(elu1(t1.x)); a[5] = f2bf(elu1(t1.y));
        a[6] = f2bf(elu1(t1.z)); a[7] = f2bf(elu1(t1.w));
        aq[ks] = a;
    }

    // ---- lookback (R9 flat clamped pattern, all loads in flight) ----
    {
        const short* base = rec_g + (size_t)(bh*NCH) * RECF;
        float pf[8] = {0.f,0.f,0.f,0.f,0.f,0.f,0.f,0.f};
        short8 rv[15];
#pragma unroll
        for (int p = 0; p < 15; ++p) {
            const int pp = (p < c) ? p : 0;        // safe, always-valid address
            rv[p] = *(const short8*)(base + (size_t)pp*RECF + tid*8);
        }
#pragma unroll
        for (int p = 0; p < 15; ++p) {
            if (p < c) {
#pragma unroll
                for (int e = 0; e < 8; ++e) pf[e] += bf2f(rv[p][e]);
            }
        }
        short8 sv;
#pragma unroll
        for (int e = 0; e < 8; ++e) sv[e] = f2bf(pf[e]);
        *(short8*)(&StT[tid >> 3][(tid & 7) * 8]) = sv;

        if (tid < 64) {                             // ksum row: one elem/lane
            float ps = 0.f;
#pragma unroll
            for (int p = 0; p < 15; ++p) {
                const int pp = (p < c) ? p : 0;
                const float kv = bf2f(base[(size_t)pp*RECF + 4096 + tid]);
                if (p < c) ps += kv;
            }
            StT[64][tid] = f2bf(ps);
        }
    }
    __syncthreads();

    const int rowb = 16*w + 4*g;

    // ---- S half A: cols s in [0,64) -> Sbh ----
#pragma unroll
    for (int tc = 0; tc < 4; ++tc) {
        f32x4 sacc = {0.f,0.f,0.f,0.f};
#pragma unroll
        for (int ks = 0; ks < 2; ++ks) {
            short8 bk = *(const short8*)(&Kb[16*tc + l15][32*ks + 8*g]);
            sacc = __builtin_amdgcn_mfma_f32_16x16x32_bf16(aq[ks], bk, sacc, 0, 0, 0);
        }
        const int colg = 16*tc + l15;
#pragma unroll
        for (int e = 0; e < 4; ++e) {
            const float sv = (colg <= rowb + e) ? sacc[e] : 0.0f;
            Sbh[rowb + e][colg] = f2bf(sv);
        }
    }
    __syncthreads();

    // ---- O += S_A.V (kj 0,1) + Q.State^T (kd 0,1); tile 4 = denominator ----
    f32x4 acc[5];
#pragma unroll
    for (int t = 0; t < 5; ++t) acc[t] = (f32x4){0.f,0.f,0.f,0.f};
#pragma unroll
    for (int kj = 0; kj < 2; ++kj) {
        short8 as = *(const short8*)(&Sbh[16*w + l15][32*kj + 8*g]);
#pragma unroll
        for (int tc = 0; tc < 5; ++tc) {
            int vrow = 16*tc + l15;
            if (vrow > 64) vrow = 64;              // clamp into ones row
            short8 bv = *(const short8*)(&VT[vrow][(32*kj + 8*g) ^ SW(vrow)]);
            acc[tc] = __builtin_amdgcn_mfma_f32_16x16x32_bf16(as, bv, acc[tc], 0, 0, 0);
        }
    }
#pragma unroll
    for (int kd = 0; kd < 2; ++kd) {
#pragma unroll
        for (int tc = 0; tc < 5; ++tc) {
            int srow = 16*tc + l15;
            if (srow > 64) srow = 64;              // clamp into ksum row
            short8 bs = *(const short8*)(&StT[srow][32*kd + 8*g]);
            acc[tc] = __builtin_amdgcn_mfma_f32_16x16x32_bf16(aq[kd], bs, acc[tc], 0, 0, 0);
        }
    }
    __syncthreads();

    // ---- S half B: cols s in [64,128) -> Sbh (local col = colg-64) ----
#pragma unroll
    for (int tc = 4; tc < 8; ++tc) {
        f32x4 sacc = {0.f,0.f,0.f,0.f};
#pragma unroll
        for (int ks = 0; ks < 2; ++ks) {
            short8 bk = *(const short8*)(&Kb[16*tc + l15][32*ks + 8*g]);
            sacc = __builtin_amdgcn_mfma_f32_16x16x32_bf16(aq[ks], bk, sacc, 0, 0, 0);
        }
        const int colg = 16*tc + l15;
#pragma unroll
        for (int e = 0; e < 4; ++e) {
            const float sv = (colg <= rowb + e) ? sacc[e] : 0.0f;
            Sbh[rowb + e][colg - 64] = f2bf(sv);
        }
    }
    __syncthreads();

    // ---- O += S_B.V (kj 2,3; global s = 64 + local) ----
#pragma unroll
    for (int kj = 2; kj < 4; ++kj) {
        short8 as = *(const short8*)(&Sbh[16*w + l15][32*(kj-2) + 8*g]);
#pragma unroll
        for (int tc = 0; tc < 5; ++tc) {
            int vrow = 16*tc + l15;
            if (vrow > 64) vrow = 64;
            short8 bv = *(const short8*)(&VT[vrow][(32*kj + 8*g) ^ SW(vrow)]);
            acc[tc] = __builtin_amdgcn_mfma_f32_16x16x32_bf16(as, bv, acc[tc], 0, 0, 0);
        }
    }

    // ---- epilogue: acc[4][e] IS the denominator in every lane ----
    float rn[4];
#pragma unroll
    for (int e = 0; e < 4; ++e) rn[e] = 1.0f / acc[4][e];
    const int rowg = c*CC + rowb;
#pragma unroll
    for (int e = 0; e < 4; ++e) {
        float* orow = out + (((size_t)b*SS + rowg + e)*HH + h)*DD + l15;
#pragma unroll
        for (int tc = 0; tc < 4; ++tc) orow[16*tc] = acc[tc][e] * rn[e];
    }
}

// ---------------------------------------------------------------------------
extern "C" void kernel_launch(void* const* d_in, const int* in_sizes, int n_in,
                              void* d_out, int out_size, void* d_ws, size_t ws_size,
                              hipStream_t stream) {
    const float* qk = (const float*)d_in[0];
    const float* v  = (const float*)d_in[1];
    float* out = (float*)d_out;

    short* rec_g = (short*)d_ws;        // 512*4160 bf16 = 4.26 MB

    k_state<<<dim3(NCHK), dim3(512), 0, stream>>>(qk, v, rec_g);
    k_out  <<<dim3(NCHK), dim3(512), 0, stream>>>(qk, v, rec_g, out);
}

// Round 15
// 30.011 us; speedup vs baseline: 1.2005x; 1.0134x over previous
//
#include <hip/hip_runtime.h>

// Problem constants (B,S,H,D fixed by the reference)
#define BB   2
#define SS   2048
#define HH   16
#define DD   64
#define CC   128               // chunk length
#define NCH  (SS/CC)           // 16 chunks per (b,h)
#define RECF (DD*DD + DD)      // 4160 elems per record: State^T rows 0..63 + ksum row 64
#define BHN  (BB*HH)           // 32
#define NCHK (BHN*NCH)         // 512 chunk-blocks

typedef __attribute__((ext_vector_type(8))) short short8;
typedef __attribute__((ext_vector_type(4))) float f32x4;

// XOR swizzle of the s-index (units of 8 shorts) by LDS row (stride-136 tiles).
#define SW(r) ((((r) >> 3) & 7) << 3)
// XOR swizzle for the pad-free Kbh[64][64] tile: col (shorts) ^= (row&7)<<3.
#define SK(r) (((r) & 7) << 3)

__device__ __forceinline__ float elu1(float x) {
    return x > 0.0f ? x + 1.0f : __expf(x);
}
__device__ __forceinline__ short f2bf(float f) {
    union { float f; unsigned u; } x; x.f = f;
    unsigned r = x.u + 0x7FFFu + ((x.u >> 16) & 1u);   // RNE
    return (short)(r >> 16);
}
__device__ __forceinline__ float bf2f(short s) {
    union { unsigned u; float f; } x; x.u = ((unsigned)(unsigned short)s) << 16;
    return x.f;
}
// pack two bf16 into one dword: lo -> short[0], hi -> short[1]
__device__ __forceinline__ unsigned pack2(float lo, float hi) {
    return (unsigned)(unsigned short)f2bf(lo)
         | ((unsigned)(unsigned short)f2bf(hi) << 16);
}

// ---------------------------------------------------------------------------
// Kernel 1 (verbatim R14): per-chunk State^T (+ksum row) = [V^T; ones] . K.
// Packed row-pair dword transpose writes (conflict-free).
// ---------------------------------------------------------------------------
__global__ __launch_bounds__(512) void k_state(const float* __restrict__ qk,
                                               const float* __restrict__ v,
                                               short* __restrict__ rec_g) {
    const int blk = blockIdx.x;
    const int c   = blk % NCH;
    const int bh  = blk / NCH;
    const int b = bh / HH, h = bh % HH;
    const int tid = threadIdx.x;
    const int w   = tid >> 6;
    const int l   = tid & 63;
    const int l15 = l & 15;
    const int g   = l >> 4;

    __shared__ short KT[64][136];   // K^T, swizzled cols
    __shared__ short VT[65][136];   // V^T + ones row 64

#pragma unroll
    for (int it = 0; it < 2; ++it) {
        const int pi   = tid + it*512;      // 0..1023
        const int r    = pi >> 4;           // row-pair index
        const int col4 = (pi & 15) * 4;     // d base
        const int s0 = c*CC + 2*r;
        const float* kp = qk + ((((size_t)b*SS + s0)*2 + 1)*HH + h)*DD + col4;
        float4 k0 = *(const float4*)kp;
        float4 k1 = *(const float4*)(kp + 2*HH*DD);
        const float* vp = v + (((size_t)b*SS + s0)*HH + h)*DD + col4;
        float4 v0 = *(const float4*)vp;
        float4 v1 = *(const float4*)(vp + HH*DD);
        const int s2 = 2*r;
        *(unsigned*)(&KT[col4+0][s2 ^ SW(col4+0)]) = pack2(elu1(k0.x), elu1(k1.x));
        *(unsigned*)(&KT[col4+1][s2 ^ SW(col4+1)]) = pack2(elu1(k0.y), elu1(k1.y));
        *(unsigned*)(&KT[col4+2][s2 ^ SW(col4+2)]) = pack2(elu1(k0.z), elu1(k1.z));
        *(unsigned*)(&KT[col4+3][s2 ^ SW(col4+3)]) = pack2(elu1(k0.w), elu1(k1.w));
        *(unsigned*)(&VT[col4+0][s2 ^ SW(col4+0)]) = pack2(v0.x, v1.x);
        *(unsigned*)(&VT[col4+1][s2 ^ SW(col4+1)]) = pack2(v0.y, v1.y);
        *(unsigned*)(&VT[col4+2][s2 ^ SW(col4+2)]) = pack2(v0.z, v1.z);
        *(unsigned*)(&VT[col4+3][s2 ^ SW(col4+3)]) = pack2(v0.w, v1.w);
    }
    if (tid < 64) *(unsigned*)(&VT[64][2*tid]) = 0x3F803F80u;   // ones row (SW(64)==0)
    __syncthreads();

    const int dtile = w & 3;
    const int half  = w >> 2;
    const int nrt   = half ? 2 : 3;
    const int rt0   = half ? 3 : 0;
    f32x4 acc1[3];
#pragma unroll
    for (int i = 0; i < 3; ++i) acc1[i] = (f32x4){0.f,0.f,0.f,0.f};
    const int krow = 16*dtile + l15;
#pragma unroll
    for (int ks = 0; ks < 4; ++ks) {
        const int cb = 32*ks + 8*g;
        short8 bk = *(const short8*)(&KT[krow][cb ^ SW(krow)]);
#pragma unroll
        for (int i = 0; i < 3; ++i) {
            if (i < nrt) {
                int arow = 16*(rt0 + i) + l15;
                if (arow > 64) arow = 64;          // clamp into ones row
                short8 a = *(const short8*)(&VT[arow][cb ^ SW(arow)]);
                acc1[i] = __builtin_amdgcn_mfma_f32_16x16x32_bf16(a, bk, acc1[i], 0, 0, 0);
            }
        }
    }
    short* rec = rec_g + (size_t)blk * RECF;
#pragma unroll
    for (int i = 0; i < 3; ++i) {
        if (i < nrt) {
            const int rt = rt0 + i;
            if (rt < 4) {
#pragma unroll
                for (int e = 0; e < 4; ++e)
                    rec[(16*rt + 4*g + e)*DD + 16*dtile + l15] = f2bf(acc1[i][e]);
            } else if (g == 0) {
                rec[4096 + 16*dtile + l15] = f2bf(acc1[i][0]);   // ksum row
            }
        }
    }
}

// ---------------------------------------------------------------------------
// Kernel 2: exclusive prefix scan over chunks (R5 structure, bf16 in/out).
// All 16 chunk loads in flight; ascending-order fp32 adds (identical order
// and values to the old in-kernel lookback -> bit-identical output).
// ---------------------------------------------------------------------------
__global__ __launch_bounds__(256) void k_scan(const short* __restrict__ rec_g,
                                              short* __restrict__ stp_g) {
    const int bh    = blockIdx.x >> 4;
    const int slice = blockIdx.x & 15;
#pragma unroll 1
    for (int ee = threadIdx.x; ee < 260; ee += 256) {
        const int elem = slice*260 + ee;
        float vals[16];
#pragma unroll
        for (int c2 = 0; c2 < 16; ++c2)
            vals[c2] = bf2f(rec_g[(size_t)(bh*NCH + c2)*RECF + elem]);
        float pref = 0.0f;
#pragma unroll
        for (int c2 = 0; c2 < 16; ++c2) {
            stp_g[(size_t)(bh*NCH + c2)*RECF + elem] = f2bf(pref);
            pref += vals[c2];
        }
    }
}

// ---------------------------------------------------------------------------
// Kernel 3: O = [S | Q] . [V;ones ; State_prefix^T;ksum], S = mask(Q K^T).
// No lookback (prefix is precomputed); half-K tile staged twice; LDS
// 53,664 B -> 3 blocks/CU. No launch-bounds min (avoid forced spills).
// ---------------------------------------------------------------------------
__global__ __launch_bounds__(512) void k_out(const float* __restrict__ qk,
                                             const float* __restrict__ v,
                                             const short* __restrict__ stp_g,
                                             float* __restrict__ out) {
    const int blk = blockIdx.x;
    const int c   = blk % NCH;
    const int bh  = blk / NCH;
    const int b = bh / HH, h = bh % HH;
    const int tid = threadIdx.x;
    const int w   = tid >> 6;
    const int l   = tid & 63;
    const int l15 = l & 15;
    const int g   = l >> 4;

    __shared__ short Kbh[64][64];   // half K tile, XOR-swizzled   8192 B
    __shared__ short Sbh[128][72];  // score half (two passes)    18432 B
    __shared__ short StT[65][72];   // prefix State^T + ksum row   9360 B
    __shared__ short VT[65][136];   // V^T + ones row 64          17680 B

    // ---- V staging: packed row-pair dword transpose (R14) ----
#pragma unroll
    for (int it = 0; it < 2; ++it) {
        const int pi   = tid + it*512;      // 0..1023
        const int r    = pi >> 4;
        const int col4 = (pi & 15) * 4;
        const int s0 = c*CC + 2*r;
        const float* vp = v + (((size_t)b*SS + s0)*HH + h)*DD + col4;
        float4 v0 = *(const float4*)vp;
        float4 v1 = *(const float4*)(vp + HH*DD);
        const int s2 = 2*r;
        *(unsigned*)(&VT[col4+0][s2 ^ SW(col4+0)]) = pack2(v0.x, v1.x);
        *(unsigned*)(&VT[col4+1][s2 ^ SW(col4+1)]) = pack2(v0.y, v1.y);
        *(unsigned*)(&VT[col4+2][s2 ^ SW(col4+2)]) = pack2(v0.z, v1.z);
        *(unsigned*)(&VT[col4+3][s2 ^ SW(col4+3)]) = pack2(v0.w, v1.w);
    }
    if (tid < 64) *(unsigned*)(&VT[64][2*tid]) = 0x3F803F80u;   // ones row

    // ---- Kbh pass-A staging (K rows 0..63) ----
#pragma unroll
    for (int it = 0; it < 2; ++it) {
        const int f    = tid + it*512;      // 0..1023
        const int row  = f >> 4;            // 0..63
        const int col4 = (f & 15) * 4;
        const int s = c*CC + row;
        float4 kq = *(const float4*)(qk + ((((size_t)b*SS + s)*2 + 1)*HH + h)*DD + col4);
        short4 kb;
        kb.x = f2bf(elu1(kq.x)); kb.y = f2bf(elu1(kq.y));
        kb.z = f2bf(elu1(kq.z)); kb.w = f2bf(elu1(kq.w));
        *(short4*)(&Kbh[row][col4 ^ SK(row)]) = kb;
    }

    // ---- Kbh pass-B data (K rows 64..127): load+convert now, LDS-write later
    short4 kbB[2];
#pragma unroll
    for (int it = 0; it < 2; ++it) {
        const int f    = tid + it*512;
        const int row  = 64 + (f >> 4);     // 64..127
        const int col4 = (f & 15) * 4;
        const int s = c*CC + row;
        float4 kq = *(const float4*)(qk + ((((size_t)b*SS + s)*2 + 1)*HH + h)*DD + col4);
        kbB[it].x = f2bf(elu1(kq.x)); kbB[it].y = f2bf(elu1(kq.y));
        kbB[it].z = f2bf(elu1(kq.z)); kbB[it].w = f2bf(elu1(kq.w));
    }

    // ---- prefix record: direct copy into StT (no accumulate) ----
    {
        const short* stp = stp_g + (size_t)blk * RECF;
        short8 st0 = *(const short8*)(stp + tid*8);
        *(short8*)(&StT[tid >> 3][(tid & 7) * 8]) = st0;
        if (tid < 8) {
            short8 st1 = *(const short8*)(stp + 4096 + tid*8);
            *(short8*)(&StT[64][tid * 8]) = st1;
        }
    }

    // ---- Q fragments (elu1 -> bf16) ----
    const int qrow = 16*w + l15;
    const float* qp = qk + ((((size_t)b*SS + (c*CC + qrow))*2 + 0)*HH + h)*DD;
    short8 aq[2];
#pragma unroll
    for (int ks = 0; ks < 2; ++ks) {
        const int k0 = 32*ks + 8*g;
        float4 t0 = *(const float4*)(qp + k0);
        float4 t1 = *(const float4*)(qp + k0 + 4);
        short8 a;
        a[0] = f2bf(elu1(t0.x)); a[1] = f2bf(elu1(t0.y));
        a[2] = f2bf(elu1(t0.z)); a[3] = f2bf(elu1(t0.w));
        a[4] = f2bf(elu1(t1.x)); a[5] = f2bf(elu1(t1.y));
        a[6] = f2bf(elu1(t1.z)); a[7] = f2bf(elu1(t1.w));
        aq[ks] = a;
    }
    __syncthreads();   // sync1: VT, Kbh-A, StT ready

    const int rowb = 16*w + 4*g;

    // ---- S pass A: global cols 0..63 from Kbh (rows 0..63) ----
#pragma unroll
    for (int tc = 0; tc < 4; ++tc) {
        const int kr = 16*tc + l15;
        f32x4 sacc = {0.f,0.f,0.f,0.f};
#pragma unroll
        for (int ks = 0; ks < 2; ++ks) {
            short8 bk = *(const short8*)(&Kbh[kr][(32*ks + 8*g) ^ SK(kr)]);
            sacc = __builtin_amdgcn_mfma_f32_16x16x32_bf16(aq[ks], bk, sacc, 0, 0, 0);
        }
        const int colg = 16*tc + l15;
#pragma unroll
        for (int e = 0; e < 4; ++e) {
            const float sv = (colg <= rowb + e) ? sacc[e] : 0.0f;
            Sbh[rowb + e][colg] = f2bf(sv);
        }
    }
    __syncthreads();   // sync2: Sbh-A ready, Kbh-A reads done

    // ---- Kbh pass-B LDS writes (hidden under the MFMAs below) ----
#pragma unroll
    for (int it = 0; it < 2; ++it) {
        const int f    = tid + it*512;
        const int row  = f >> 4;            // local row 0..63 (global 64..127)
        const int col4 = (f & 15) * 4;
        *(short4*)(&Kbh[row][col4 ^ SK(row)]) = kbB[it];
    }

    // ---- O = S_A.V (kj 0,1) + Q.State^T (kd 0,1); tile 4 = denominator ----
    f32x4 acc[5];
#pragma unroll
    for (int t = 0; t < 5; ++t) acc[t] = (f32x4){0.f,0.f,0.f,0.f};
#pragma unroll
    for (int kj = 0; kj < 2; ++kj) {
        short8 as = *(const short8*)(&Sbh[16*w + l15][32*kj + 8*g]);
#pragma unroll
        for (int tc = 0; tc < 5; ++tc) {
            int vrow = 16*tc + l15;
            if (vrow > 64) vrow = 64;              // clamp into ones row
            short8 bv = *(const short8*)(&VT[vrow][(32*kj + 8*g) ^ SW(vrow)]);
            acc[tc] = __builtin_amdgcn_mfma_f32_16x16x32_bf16(as, bv, acc[tc], 0, 0, 0);
        }
    }
#pragma unroll
    for (int kd = 0; kd < 2; ++kd) {
#pragma unroll
        for (int tc = 0; tc < 5; ++tc) {
            int srow = 16*tc + l15;
            if (srow > 64) srow = 64;              // clamp into ksum row
            short8 bs = *(const short8*)(&StT[srow][32*kd + 8*g]);
            acc[tc] = __builtin_amdgcn_mfma_f32_16x16x32_bf16(aq[kd], bs, acc[tc], 0, 0, 0);
        }
    }
    __syncthreads();   // sync3: Kbh-B visible; Sbh-A reads done

    // ---- S pass B: global cols 64..127 from Kbh (rows 64..127) ----
#pragma unroll
    for (int tc = 4; tc < 8; ++tc) {
        const int kr = 16*(tc-4) + l15;
        f32x4 sacc = {0.f,0.f,0.f,0.f};
#pragma unroll
        for (int ks = 0; ks < 2; ++ks) {
            short8 bk = *(const short8*)(&Kbh[kr][(32*ks + 8*g) ^ SK(kr)]);
            sacc = __builtin_amdgcn_mfma_f32_16x16x32_bf16(aq[ks], bk, sacc, 0, 0, 0);
        }
        const int colg = 16*tc + l15;
#pragma unroll
        for (int e = 0; e < 4; ++e) {
            const float sv = (colg <= rowb + e) ? sacc[e] : 0.0f;
            Sbh[rowb + e][colg - 64] = f2bf(sv);
        }
    }
    __syncthreads();   // sync4: Sbh-B ready

    // ---- O += S_B.V (kj 2,3; global s = 64 + local) ----
#pragma unroll
    for (int kj = 2; kj < 4; ++kj) {
        short8 as = *(const short8*)(&Sbh[16*w + l15][32*(kj-2) + 8*g]);
#pragma unroll
        for (int tc = 0; tc < 5; ++tc) {
            int vrow = 16*tc + l15;
            if (vrow > 64) vrow = 64;
            short8 bv = *(const short8*)(&VT[vrow][(32*kj + 8*g) ^ SW(vrow)]);
            acc[tc] = __builtin_amdgcn_mfma_f32_16x16x32_bf16(as, bv, acc[tc], 0, 0, 0);
        }
    }

    // ---- epilogue: acc[4][e] IS the denominator in every lane ----
    float rn[4];
#pragma unroll
    for (int e = 0; e < 4; ++e) rn[e] = 1.0f / acc[4][e];
    const int rowg = c*CC + rowb;
#pragma unroll
    for (int e = 0; e < 4; ++e) {
        float* orow = out + (((size_t)b*SS + rowg + e)*HH + h)*DD + l15;
#pragma unroll
        for (int tc = 0; tc < 4; ++tc) orow[16*tc] = acc[tc][e] * rn[e];
    }
}

// ---------------------------------------------------------------------------
extern "C" void kernel_launch(void* const* d_in, const int* in_sizes, int n_in,
                              void* d_out, int out_size, void* d_ws, size_t ws_size,
                              hipStream_t stream) {
    const float* qk = (const float*)d_in[0];
    const float* v  = (const float*)d_in[1];
    float* out = (float*)d_out;

    short* rec_g = (short*)d_ws;                   // 512*4160 bf16 = 4.26 MB
    short* stp_g = rec_g + (size_t)NCHK * RECF;    // 512*4160 bf16 = 4.26 MB

    k_state<<<dim3(NCHK), dim3(512), 0, stream>>>(qk, v, rec_g);
    k_scan <<<dim3(NCHK), dim3(256), 0, stream>>>(rec_g, stp_g);
    k_out  <<<dim3(NCHK), dim3(512), 0, stream>>>(qk, v, stp_g, out);
}